// Round 12
// baseline (154.610 us; speedup 1.0000x reference)
//
#include <hip/hip_runtime.h>
#include <hip/hip_bf16.h>

// Problem dims (fixed by reference): B=512, Q=64, S=36, D=1024, SIM=256
#define BB 512
#define QQ 64
#define SS 36
#define DD 1024
#define SIM 256

typedef unsigned short u16x8 __attribute__((ext_vector_type(8)));
typedef __bf16 bf16x8 __attribute__((ext_vector_type(8)));
typedef float f32x4 __attribute__((ext_vector_type(4)));
typedef unsigned short us;

__device__ __forceinline__ us f2bf(float f) {
  unsigned u = __float_as_uint(f);
  u += 0x7FFFu + ((u >> 16) & 1u);   // round-to-nearest-even
  return (us)(u >> 16);
}
__device__ __forceinline__ float bf2f(us h) {
  return __uint_as_float(((unsigned)h) << 16);
}

// ---------------------------------------------------------------------------
// K0: one-shot W (256x1024 f32) -> bf16 row-major copy in ws. L2-resident.
// ---------------------------------------------------------------------------
__global__ __launch_bounds__(256) void k0_w16(const float* __restrict__ W,
                                              us* __restrict__ W16) {
  int i = blockIdx.x * 256 + threadIdx.x;  // 65536 float4s
  float4 v = ((const float4*)W)[i];
  ushort4 p;
  p.x = f2bf(v.x); p.y = f2bf(v.y); p.z = f2bf(v.z); p.w = f2bf(v.w);
  ((ushort4*)W16)[i] = p;
}

// ---------------------------------------------------------------------------
// K_FUSED v4: one batch per block, 1024 thr (16 waves = 4/SIMD), 155.6KB
// dyn LDS, 1 block/CU. vs v3: (a) 2x waves for latency hiding; (b) qm
// staging double-buffered, ONE barrier per chunk, loads for ch+1 issued
// before MFMA(ch) (sched_barrier pins them) so HBM latency hides under
// compute + other waves. Bytes identical to v3 (input+output floor).
//
// Phase A roles: waves 0-11 scores (1 tile each: mt=w>>2, nt=w&3);
//   waves 12-14 G row-blocks; wave 15 staging only.
// Phase B roles: waves 0-7 wc+A16 (d-cols w*16..+16); all 16 waves sim GEMM
//   (n-tile cols w*16..+16).
//
// LDS map:
//   [0,99072)        ctxL us[48][1032] full-D ctx (rows 36-47 zero)
//   [99072,116480)   qmA us[64][136] | sc f32[48][68] | A16s us[64][136]
//   [116480,133888)  qmB us[64][136]
//   [133888,143104)  P16s us[64][72]
//   [143104,150016)  Gf16 us[48][72]
//   [150016,151040)  biasL f32[256]
//   [151040,151296)  rnL f32[64]
//   [151296,155648)  rsum f32[64*17]
// ---------------------------------------------------------------------------
#define KF_LDS 155648

template <bool USE_W16>
__global__ __launch_bounds__(1024, 4) void k_fused(
    const float* __restrict__ query, const float* __restrict__ context,
    const float* __restrict__ matrix, const float* __restrict__ Wm,
    const float* __restrict__ bvec, const int* __restrict__ smoothp,
    const us* __restrict__ W16, float* __restrict__ out) {
  extern __shared__ __align__(16) char smem[];
  us* ctxL = (us*)smem;                    // [48][1032]
  us* qmA = (us*)(smem + 99072);           // [64][136]
  us* qmB = (us*)(smem + 116480);          // [64][136]
  float* sc = (float*)(smem + 99072);      // [48][68]  (bridge)
  us* A16s = (us*)(smem + 99072);          // [64][136] (phase B)
  us* P16s = (us*)(smem + 133888);         // [64][72]
  us* Gf16L = (us*)(smem + 143104);        // [48][72]
  float* biasL = (float*)(smem + 150016);  // [256]
  float* rnL = (float*)(smem + 151040);    // [64]
  float* rsum = (float*)(smem + 151296);   // [64*17]

  const int t = threadIdx.x, bb = blockIdx.x;
  const int lane = t & 63, w = t >> 6;     // w in 0..15
  const int ml = lane & 15, kg = lane >> 4;
  const float smf = (float)smoothp[0];

  // init: zero ctxL rows 36-47, P16/Gf16 pads; load bias
  for (int idx = t; idx < 6192; idx += 1024)
    ((unsigned*)(ctxL + 36 * 1032))[idx] = 0;
  for (int idx = t; idx < 2304; idx += 1024) ((unsigned*)P16s)[idx] = 0;
  for (int idx = t; idx < 1728; idx += 1024) ((unsigned*)Gf16L)[idx] = 0;
  if (t < 256) biasL[t] = bvec[t];

  // per-thread staging slot (1024 slots: row = t>>4, 8 consecutive d)
  const int srow = t >> 4, sc8 = t & 15;
  const float* qrow = query + ((size_t)bb * QQ + srow) * DD + sc8 * 8;
  const float* mrow = matrix + ((size_t)bb * QQ + srow) * DD + sc8 * 8;
  const float* crow = context + ((size_t)bb * SS + (srow < 36 ? srow : 0)) * DD + sc8 * 8;
  const float* qcol = query + (size_t)bb * QQ * DD + w * 16 + ml;  // stash (w<8)

  // register stash of phase-B query slice (waves 0-7):
  u16x8 qr0[8], qr1[8];

  // unified accumulators: scores waves use acc[0]; G waves use acc[0..2]
  f32x4 acc[3];
#pragma unroll
  for (int j = 0; j < 3; ++j) acc[j] = (f32x4){0.f, 0.f, 0.f, 0.f};

  // ---- prologue: stage chunk 0 into qmA + ctxL cols [0,128) ----
  {
    float4 a0 = *(const float4*)(qrow + 0), a1 = *(const float4*)(qrow + 4);
    float4 m0 = *(const float4*)(mrow + 0), m1 = *(const float4*)(mrow + 4);
    u16x8 pk;
    pk[0] = f2bf(a0.x * m0.x); pk[1] = f2bf(a0.y * m0.y);
    pk[2] = f2bf(a0.z * m0.z); pk[3] = f2bf(a0.w * m0.w);
    pk[4] = f2bf(a1.x * m1.x); pk[5] = f2bf(a1.y * m1.y);
    pk[6] = f2bf(a1.z * m1.z); pk[7] = f2bf(a1.w * m1.w);
    *(u16x8*)&qmA[srow * 136 + sc8 * 8] = pk;
    if (t < 576) {
      float4 c0 = *(const float4*)(crow + 0), c1 = *(const float4*)(crow + 4);
      u16x8 ck;
      ck[0] = f2bf(c0.x); ck[1] = f2bf(c0.y); ck[2] = f2bf(c0.z); ck[3] = f2bf(c0.w);
      ck[4] = f2bf(c1.x); ck[5] = f2bf(c1.y); ck[6] = f2bf(c1.z); ck[7] = f2bf(c1.w);
      *(u16x8*)&ctxL[srow * 1032 + sc8 * 8] = ck;
    }
  }
  __syncthreads();

  // ================= Phase A main loop: one barrier per chunk =============
#pragma unroll
  for (int ch = 0; ch < 8; ++ch) {
    const int d0 = ch * 128, dn = d0 + 128;
    // A: issue loads for chunk ch+1 (main) and stash chunk ch (L2-hot)
    float4 a0, a1, m0, m1, c0, c1;
    if (ch < 7) {
      a0 = *(const float4*)(qrow + dn); a1 = *(const float4*)(qrow + dn + 4);
      m0 = *(const float4*)(mrow + dn); m1 = *(const float4*)(mrow + dn + 4);
      if (t < 576) {
        c0 = *(const float4*)(crow + dn); c1 = *(const float4*)(crow + dn + 4);
      }
    }
    float sv[16];
    if (w < 8) {
#pragma unroll
      for (int j = 0; j < 16; ++j) {
        int q = (j >> 2) * 16 + kg * 4 + (j & 3);
        sv[j] = qcol[(size_t)q * DD + d0];
      }
    }
    __builtin_amdgcn_sched_barrier(0);  // keep load issue before MFMA
    // B: MFMA(ch)
    const us* qmCur = (ch & 1) ? qmB : qmA;
#pragma unroll
    for (int ks = 0; ks < 4; ++ks) {
      const int ko = ks * 32 + kg * 8;
      if (w < 12) {  // scores tile (mt = w>>2, nt = w&3)
        const int mt = w >> 2, nt = w & 3;
        bf16x8 bq = __builtin_bit_cast(bf16x8, *(const u16x8*)&qmCur[(nt * 16 + ml) * 136 + ko]);
        bf16x8 af = __builtin_bit_cast(
            bf16x8, *(const u16x8*)&ctxL[(mt * 16 + ml) * 1032 + d0 + ko]);
        acc[0] = __builtin_amdgcn_mfma_f32_16x16x32_bf16(af, bq, acc[0], 0, 0, 0);
      } else if (w < 15) {  // G row-block w-12
        bf16x8 ai = __builtin_bit_cast(
            bf16x8, *(const u16x8*)&ctxL[((w - 12) * 16 + ml) * 1032 + d0 + ko]);
#pragma unroll
        for (int j = 0; j < 3; ++j) {
          bf16x8 aj = __builtin_bit_cast(
              bf16x8, *(const u16x8*)&ctxL[(j * 16 + ml) * 1032 + d0 + ko]);
          acc[j] = __builtin_amdgcn_mfma_f32_16x16x32_bf16(ai, aj, acc[j], 0, 0, 0);
        }
      }
    }
    // C: convert+write staged data for ch+1; pack stash(ch)
    if (ch < 7) {
      us* qdst = ((ch + 1) & 1) ? qmB : qmA;
      u16x8 pk;
      pk[0] = f2bf(a0.x * m0.x); pk[1] = f2bf(a0.y * m0.y);
      pk[2] = f2bf(a0.z * m0.z); pk[3] = f2bf(a0.w * m0.w);
      pk[4] = f2bf(a1.x * m1.x); pk[5] = f2bf(a1.y * m1.y);
      pk[6] = f2bf(a1.z * m1.z); pk[7] = f2bf(a1.w * m1.w);
      *(u16x8*)&qdst[srow * 136 + sc8 * 8] = pk;
      if (t < 576) {
        u16x8 ck;
        ck[0] = f2bf(c0.x); ck[1] = f2bf(c0.y); ck[2] = f2bf(c0.z); ck[3] = f2bf(c0.w);
        ck[4] = f2bf(c1.x); ck[5] = f2bf(c1.y); ck[6] = f2bf(c1.z); ck[7] = f2bf(c1.w);
        *(u16x8*)&ctxL[srow * 1032 + dn + sc8 * 8] = ck;
      }
    }
    if (w < 8) {
      u16x8 s0, s1;
#pragma unroll
      for (int j = 0; j < 8; ++j) {
        s0[j] = f2bf(sv[j]);
        s1[j] = f2bf(sv[8 + j]);
      }
      qr0[ch] = s0;
      qr1[ch] = s1;
    }
    __syncthreads();  // D
  }

  // epilogue A: leaky -> sc (aliases qmA, dead now); G -> Gf16
  if (w < 12) {
    const int mt = w >> 2, nt = w & 3;
#pragma unroll
    for (int ii = 0; ii < 4; ++ii) {
      float v = acc[0][ii];
      v = v > 0.f ? v : 0.1f * v;
      sc[(mt * 16 + kg * 4 + ii) * 68 + nt * 16 + ml] = v;
    }
  } else if (w < 15) {
#pragma unroll
    for (int j = 0; j < 3; ++j)
#pragma unroll
      for (int ii = 0; ii < 4; ++ii)
        Gf16L[((w - 12) * 16 + kg * 4 + ii) * 72 + j * 16 + ml] = f2bf(acc[j][ii]);
  }
  __syncthreads();

  if (t < 36) {  // l2norm over q per row s
    float ssum = 0.f;
    for (int qi = 0; qi < 64; ++qi) { float v = sc[t * 68 + qi]; ssum = fmaf(v, v, ssum); }
    float rn = 1.f / (sqrtf(ssum) + 1e-8f);
    for (int qi = 0; qi < 64; ++qi) sc[t * 68 + qi] *= rn;
  }
  __syncthreads();

  if (t < 64) {  // softmax over s per column q -> P16
    float mx = -1e30f;
    for (int s2 = 0; s2 < 36; ++s2) mx = fmaxf(mx, sc[s2 * 68 + t]);
    float sum = 0.f;
    float ev[36];
    for (int s2 = 0; s2 < 36; ++s2) {
      float e = __expf((sc[s2 * 68 + t] - mx) * smf);
      ev[s2] = e;
      sum += e;
    }
    float rs = 1.f / sum;
#pragma unroll
    for (int s2 = 0; s2 < 36; ++s2) P16s[t * 72 + s2] = f2bf(ev[s2] * rs);
  }
  __syncthreads();

  // ================= Bridge: V = P.G^T -> rn_q =================
  if (w < 3) {
    f32x4 accv[4];
#pragma unroll
    for (int mt = 0; mt < 4; ++mt) accv[mt] = (f32x4){0.f, 0.f, 0.f, 0.f};
#pragma unroll
    for (int ks = 0; ks < 2; ++ks) {
      const int ko = ks * 32 + kg * 8;
      bf16x8 gfr = __builtin_bit_cast(bf16x8, *(const u16x8*)&Gf16L[(w * 16 + ml) * 72 + ko]);
#pragma unroll
      for (int mt = 0; mt < 4; ++mt) {
        bf16x8 pf = __builtin_bit_cast(bf16x8, *(const u16x8*)&P16s[(mt * 16 + ml) * 72 + ko]);
        accv[mt] = __builtin_amdgcn_mfma_f32_16x16x32_bf16(pf, gfr, accv[mt], 0, 0, 0);
      }
    }
#pragma unroll
    for (int mt = 0; mt < 4; ++mt)
#pragma unroll
      for (int ii = 0; ii < 4; ++ii) {
        int q = mt * 16 + kg * 4 + ii;
        float vv = accv[mt][ii] * bf2f(P16s[q * 72 + w * 16 + ml]);
        vv += __shfl_xor(vv, 1);
        vv += __shfl_xor(vv, 2);
        vv += __shfl_xor(vv, 4);
        vv += __shfl_xor(vv, 8);
        if (ml == 0) rsum[q * 4 + w] = vv;
      }
  }
  __syncthreads();
  if (t < 64) {
    float s2 = rsum[t * 4] + rsum[t * 4 + 1] + rsum[t * 4 + 2];
    rnL[t] = 1.f / (sqrtf(s2) + 1e-8f);
  }
  __syncthreads();

  // ================= Phase B: wc -> A -> sim GEMM (no input globals) ======
  f32x4 accs[4];
#pragma unroll
  for (int mt = 0; mt < 4; ++mt) accs[mt] = (f32x4){0.f, 0.f, 0.f, 0.f};

#pragma unroll
  for (int ch = 0; ch < 8; ++ch) {
    const int d0 = ch * 128;
    // (c) wc = P.C : waves 0-7, d-cols [w*16, w*16+16)
    f32x4 aw[4];
#pragma unroll
    for (int mt = 0; mt < 4; ++mt) aw[mt] = (f32x4){0.f, 0.f, 0.f, 0.f};
    if (w < 8) {
      const int ncol = d0 + w * 16 + ml;
      u16x8 g0;
#pragma unroll
      for (int j = 0; j < 8; ++j) g0[j] = ctxL[(kg * 8 + j) * 1032 + ncol];
      bf16x8 bfr0 = __builtin_bit_cast(bf16x8, g0);
#pragma unroll
      for (int mt = 0; mt < 4; ++mt) {
        bf16x8 af = __builtin_bit_cast(bf16x8, *(const u16x8*)&P16s[(mt * 16 + ml) * 72 + kg * 8]);
        aw[mt] = __builtin_amdgcn_mfma_f32_16x16x32_bf16(af, bfr0, aw[mt], 0, 0, 0);
      }
      u16x8 g1;
#pragma unroll
      for (int j = 0; j < 8; ++j)
        g1[j] = (kg < 2) ? ctxL[(32 + kg * 8 + j) * 1032 + ncol] : (us)0;
      bf16x8 bfr1 = __builtin_bit_cast(bf16x8, g1);
#pragma unroll
      for (int mt = 0; mt < 4; ++mt) {
        bf16x8 af =
            __builtin_bit_cast(bf16x8, *(const u16x8*)&P16s[(mt * 16 + ml) * 72 + 32 + kg * 8]);
        aw[mt] = __builtin_amdgcn_mfma_f32_16x16x32_bf16(af, bfr1, aw[mt], 0, 0, 0);
      }
    }
    __syncthreads();  // prev chunk's (f) reads of A16s done
    // (d) A = (q - wc*rn)^2 -> A16s (waves 0-7, query from register stash)
    if (w < 8) {
#pragma unroll
      for (int mt = 0; mt < 4; ++mt)
#pragma unroll
        for (int ii = 0; ii < 4; ++ii) {
          int q = mt * 16 + kg * 4 + ii;
          const int e = mt * 4 + ii;
          float qv = bf2f(e < 8 ? qr0[ch][e] : qr1[ch][e - 8]);
          float av = qv - aw[mt][ii] * rnL[q];
          A16s[q * 136 + w * 16 + ml] = f2bf(av * av);
        }
    }
    __syncthreads();
    // (f) sim GEMM: all 16 waves, n-tile cols [w*16, w*16+16)
#pragma unroll
    for (int ks = 0; ks < 4; ++ks) {
      const int ko = ks * 32 + kg * 8;
      bf16x8 bfr;
      if constexpr (USE_W16) {
        bfr = __builtin_bit_cast(
            bf16x8, *(const u16x8*)&W16[(size_t)(w * 16 + ml) * DD + d0 + ko]);
      } else {
        const float4* wp = (const float4*)&Wm[(size_t)(w * 16 + ml) * DD + d0 + ko];
        float4 x = wp[0], y = wp[1];
        u16x8 pk;
        pk[0] = f2bf(x.x); pk[1] = f2bf(x.y); pk[2] = f2bf(x.z); pk[3] = f2bf(x.w);
        pk[4] = f2bf(y.x); pk[5] = f2bf(y.y); pk[6] = f2bf(y.z); pk[7] = f2bf(y.w);
        bfr = __builtin_bit_cast(bf16x8, pk);
      }
#pragma unroll
      for (int mt = 0; mt < 4; ++mt) {
        bf16x8 af = __builtin_bit_cast(bf16x8, *(const u16x8*)&A16s[(mt * 16 + ml) * 136 + ko]);
        accs[mt] = __builtin_amdgcn_mfma_f32_16x16x32_bf16(af, bfr, accs[mt], 0, 0, 0);
      }
    }
  }
  __syncthreads();

  // ================= Epilogue B: +bias, l2norm(SIM), store =================
#pragma unroll
  for (int mt = 0; mt < 4; ++mt)
#pragma unroll
    for (int ii = 0; ii < 4; ++ii) {
      int q = mt * 16 + kg * 4 + ii;
      float v = accs[mt][ii] + biasL[w * 16 + ml];
      float partial = v * v;
      partial += __shfl_xor(partial, 1);
      partial += __shfl_xor(partial, 2);
      partial += __shfl_xor(partial, 4);
      partial += __shfl_xor(partial, 8);
      if (ml == 0) rsum[q * 17 + w] = partial;
    }
  __syncthreads();
  if (t < 64) {
    float ssum = 0.f;
#pragma unroll
    for (int w2 = 0; w2 < 16; ++w2) ssum += rsum[t * 17 + w2];
    rnL[t] = 1.f / (sqrtf(ssum) + 1e-8f);
  }
  __syncthreads();
#pragma unroll
  for (int mt = 0; mt < 4; ++mt)
#pragma unroll
    for (int ii = 0; ii < 4; ++ii) {
      int q = mt * 16 + kg * 4 + ii;
      int col = w * 16 + ml;
      float v = accs[mt][ii] + biasL[col];
      out[((size_t)bb * QQ + q) * SIM + col] = v * rnL[q];
    }
}

extern "C" void kernel_launch(void* const* d_in, const int* in_sizes, int n_in,
                              void* d_out, int out_size, void* d_ws, size_t ws_size,
                              hipStream_t stream) {
  const float* query = (const float*)d_in[0];
  const float* context = (const float*)d_in[1];
  const float* matrix = (const float*)d_in[2];
  const float* Wm = (const float*)d_in[3];
  const float* bvec = (const float*)d_in[4];
  const int* smoothp = (const int*)d_in[5];
  float* out = (float*)d_out;

  us* W16 = (us*)d_ws;
  const bool useW16 = ws_size >= (size_t)SIM * DD * 2;

  hipFuncSetAttribute((const void*)k_fused<true>,
                      hipFuncAttributeMaxDynamicSharedMemorySize, KF_LDS);
  hipFuncSetAttribute((const void*)k_fused<false>,
                      hipFuncAttributeMaxDynamicSharedMemorySize, KF_LDS);

  if (useW16) {
    k0_w16<<<dim3(SIM * DD / 1024), dim3(256), 0, stream>>>(Wm, W16);
    k_fused<true><<<dim3(BB), dim3(1024), KF_LDS, stream>>>(query, context, matrix, Wm,
                                                            bvec, smoothp, W16, out);
  } else {
    k_fused<false><<<dim3(BB), dim3(1024), KF_LDS, stream>>>(query, context, matrix, Wm,
                                                             bvec, smoothp, W16, out);
  }
}